// Round 1
// baseline (375.496 us; speedup 1.0000x reference)
//
#include <hip/hip_runtime.h>

#define HIDDEN 1024
#define NG 20
#define BATCH 512
#define SEQ 1024
#define VOCAB 128

// output offsets (flat concat of (wind, kappa, phi))
#define WIND_OFF  0
#define KAPPA_OFF (BATCH * VOCAB)                 // 65536
#define PHI_OFF   (BATCH * VOCAB + BATCH * NG)    // 75776

__global__ __launch_bounds__(512) void window_fused(
    const float*  __restrict__ win,    // [B, H]
    const float4* __restrict__ sh4,    // [B, U, V/4]
    const float*  __restrict__ kprev,  // [B, NG]
    const float*  __restrict__ W,      // [3*NG, H]
    const float*  __restrict__ bias,   // [3*NG]
    float*        __restrict__ out)    // wind | kappa | phi
{
    const int b    = blockIdx.x;
    const int tid  = threadIdx.x;
    const int lane = tid & 63;
    const int wave = tid >> 6;   // 0..7

    __shared__ float lin_s[3 * NG];
    __shared__ float alpha_s[NG], beta_s[NG], kappa_s[NG];
    __shared__ float phi_s[SEQ];
    __shared__ float red[16][VOCAB];

    // ---- Phase A: lin[j] = win[b,:] . W[j,:] + bias[j]  (wave per j) ----
    const float* wrow = win + (size_t)b * HIDDEN;
    for (int j = wave; j < 3 * NG; j += 8) {
        const float* Wrow = W + (size_t)j * HIDDEN;
        float acc = 0.f;
        #pragma unroll
        for (int t = 0; t < HIDDEN / 64; ++t)
            acc = fmaf(wrow[t * 64 + lane], Wrow[t * 64 + lane], acc);
        #pragma unroll
        for (int off = 32; off > 0; off >>= 1)
            acc += __shfl_down(acc, off, 64);
        if (lane == 0) lin_s[j] = acc + bias[j];
    }
    __syncthreads();

    // ---- Phase B: gates ----
    if (tid < 3 * NG) {
        float e = __expf(lin_s[tid]);
        if (tid < NG) {
            alpha_s[tid] = e;
        } else if (tid < 2 * NG) {
            beta_s[tid - NG] = e;
        } else {
            int k = tid - 2 * NG;
            float kp = kprev[(size_t)b * NG + k] + e * 0.05f;
            kappa_s[k] = kp;
            out[KAPPA_OFF + (size_t)b * NG + k] = kp;
        }
    }
    __syncthreads();

    // ---- Phase C: phi[u] = sum_k alpha_k * exp(-beta_k * (kappa_k - u)^2) ----
    for (int u = tid; u < SEQ; u += 512) {
        float uu = (float)u;
        float p = 0.f;
        #pragma unroll
        for (int k = 0; k < NG; ++k) {
            float d = kappa_s[k] - uu;
            p = fmaf(alpha_s[k], __expf(-beta_s[k] * d * d), p);
        }
        phi_s[u] = p;
        out[PHI_OFF + (size_t)b * SEQ + u] = p;
    }
    __syncthreads();

    // ---- Phase D: wind[b,v] = sum_u phi[u] * sentence_hot[b,u,v] ----
    const int vq = tid & 31;   // float4 column group: v = 4*vq .. 4*vq+3
    const int ug = tid >> 5;   // 0..15 u-row group
    const float4* base = sh4 + (size_t)b * SEQ * (VOCAB / 4);
    float4 acc = make_float4(0.f, 0.f, 0.f, 0.f);
    for (int u = ug; u < SEQ; u += 16) {
        float4 s = base[(size_t)u * (VOCAB / 4) + vq];
        float  p = phi_s[u];
        acc.x = fmaf(p, s.x, acc.x);
        acc.y = fmaf(p, s.y, acc.y);
        acc.z = fmaf(p, s.z, acc.z);
        acc.w = fmaf(p, s.w, acc.w);
    }
    *(float4*)&red[ug][vq * 4] = acc;
    __syncthreads();

    if (tid < VOCAB) {
        float s = 0.f;
        #pragma unroll
        for (int g = 0; g < 16; ++g) s += red[g][tid];
        out[WIND_OFF + (size_t)b * VOCAB + tid] = s;
    }
}

extern "C" void kernel_launch(void* const* d_in, const int* in_sizes, int n_in,
                              void* d_out, int out_size, void* d_ws, size_t ws_size,
                              hipStream_t stream) {
    const float*  win   = (const float*)d_in[0];
    const float4* sh4   = (const float4*)d_in[1];
    const float*  kprev = (const float*)d_in[2];
    const float*  W     = (const float*)d_in[3];
    const float*  bias  = (const float*)d_in[4];
    float* out = (float*)d_out;

    window_fused<<<dim3(BATCH), dim3(512), 0, stream>>>(win, sh4, kprev, W, bias, out);
}